// Round 4
// baseline (141.263 us; speedup 1.0000x reference)
//
#include <hip/hip_runtime.h>
#include <hip/hip_bf16.h>

// Wide_BasicBlock_Q: DoReFa-quantized residual block on MI355X (gfx950).
// Pipeline:
//   k_init / k_wmax      : max|tanh(w)| for w1, w2 (atomicMax on float bits)
//   k_bnprep             : BN scale/shift for bn1, bn_s, bn2
//   k_wq x3              : quantize+prepack weights -> bf16 [kstep][co][32]
//   k_a1                 : a1 = actq4(bn1(x)) -> NHWC bf16; asc = bn_s(x) at
//                          stride-2 positions -> compact NHWC bf16
//   conv_mfma<...,MODE=1>: shortcut 1x1 GEMM -> d_out (fp32)
//   conv_mfma<...,MODE=0>: conv1, epilogue bn2+actq4 -> a2 NHWC bf16
//   conv_mfma<...,MODE=2>: conv2, epilogue += d_out (shortcut), write d_out

typedef __bf16 bf16x8 __attribute__((ext_vector_type(8)));
typedef float f32x4 __attribute__((ext_vector_type(4)));

#define EPSV 1e-5f

__global__ void k_init(float* wmax) {
    if (threadIdx.x < 2) wmax[threadIdx.x] = 0.f;
}

__global__ __launch_bounds__(256) void k_wmax(const float* __restrict__ w1,
                                              const float* __restrict__ w2,
                                              float* wmax) {
    int sel = blockIdx.x >> 5;                 // 0: w1, 1: w2
    const float* src = sel ? w2 : w1;
    int cnt = sel ? 128 * 128 * 9 : 128 * 64 * 9;
    float m = 0.f;
    for (int i = (blockIdx.x & 31) * 256 + threadIdx.x; i < cnt; i += 32 * 256)
        m = fmaxf(m, fabsf(tanhf(src[i])));
#pragma unroll
    for (int off = 32; off > 0; off >>= 1)
        m = fmaxf(m, __shfl_down(m, off));
    __shared__ float red[4];
    if ((threadIdx.x & 63) == 0) red[threadIdx.x >> 6] = m;
    __syncthreads();
    if (threadIdx.x == 0) {
        m = fmaxf(fmaxf(red[0], red[1]), fmaxf(red[2], red[3]));
        atomicMax((int*)(wmax + sel), __float_as_int(m));  // all values >= 0
    }
}

// bnp layout (floats): [0:64)=sc1 [64:128)=sh1 [128:192)=scs [192:256)=shs
//                      [256:384)=sc2 [384:512)=sh2
__global__ void k_bnprep(const float* g1, const float* b1, const float* m1, const float* v1,
                         const float* g2, const float* b2, const float* m2, const float* v2,
                         const float* gs, const float* bs, const float* ms, const float* vs,
                         float* bnp) {
    int c = threadIdx.x;  // blockDim = 128
    if (c < 64) {
        float s = g1[c] * rsqrtf(v1[c] + EPSV);
        bnp[c] = s;          bnp[64 + c] = b1[c] - m1[c] * s;
        float s2 = gs[c] * rsqrtf(vs[c] + EPSV);
        bnp[128 + c] = s2;   bnp[192 + c] = bs[c] - ms[c] * s2;
    }
    float s = g2[c] * rsqrtf(v2[c] + EPSV);
    bnp[256 + c] = s;        bnp[384 + c] = b2[c] - m2[c] * s;
}

// Quantize (DoReFa) + prepack weights: dst[((s*128 + co)*32 + kk)] with
// k = s*32+kk, k-order = khw*CIN + ci, src layout [co][ci][kh][kw].
template <int CIN, int KHW, bool QUANT>
__global__ __launch_bounds__(256) void k_wq(const float* __restrict__ w,
                                            __bf16* __restrict__ dst,
                                            const float* __restrict__ wmax, int total) {
    int idx = blockIdx.x * 256 + threadIdx.x;
    if (idx >= total) return;
    int kk = idx & 31;
    int co = (idx >> 5) & 127;
    int s = idx >> 12;
    int k = s * 32 + kk;
    int khw = k / CIN;
    int ci = k % CIN;
    float v = w[(co * CIN + ci) * KHW + khw];
    float outv;
    if constexpr (QUANT) {
        float M = *wmax;
        float t = tanhf(v) / (2.f * M) + 0.5f;          // in [0,1]
        outv = 2.f * (rintf(t * 15.f) * (1.f / 15.f)) - 1.f;
    } else {
        outv = v;
    }
    dst[idx] = (__bf16)outv;
}

// a1 = actq4(bn1(x)) -> NHWC bf16 [256][32][32][64]
// asc = bn_s(x) at even (h,w) -> NHWC bf16 [256][16][16][64]
__global__ __launch_bounds__(256) void k_a1(const float* __restrict__ x,
                                            const float* __restrict__ bnp,
                                            __bf16* __restrict__ a1,
                                            __bf16* __restrict__ asc) {
    __shared__ __align__(16) __bf16 l1[32][72];
    __shared__ __align__(16) __bf16 l2[16][72];
    __shared__ float s1[64], h1[64], ss[64], hs[64];
    int t = threadIdx.x;
    int n = blockIdx.x >> 5, h = blockIdx.x & 31;
    if (t < 64) {
        s1[t] = bnp[t];       h1[t] = bnp[64 + t];
        ss[t] = bnp[128 + t]; hs[t] = bnp[192 + t];
    }
    __syncthreads();
    bool he = (h & 1) == 0;
#pragma unroll
    for (int i = 0; i < 8; ++i) {
        int idx = t + i * 256;          // over (c,w): c=idx>>5, w=idx&31
        int c = idx >> 5, w = idx & 31;
        float xv = x[((n * 64 + c) * 32 + h) * 32 + w];
        float v = xv * s1[c] + h1[c];
        float q = rintf(fminf(fmaxf(v, 0.f), 1.f) * 15.f) * (1.f / 15.f);
        l1[w][c] = (__bf16)q;
        if (he && !(w & 1)) l2[w >> 1][c] = (__bf16)(xv * ss[c] + hs[c]);
    }
    __syncthreads();
    {
        int o = t * 8;                  // over (w,c): w=o>>6, c=o&63
        int w = o >> 6, c = o & 63;
        *(uint4*)(a1 + (((size_t)(n * 32 + h)) * 32 + w) * 64 + c) = *(uint4*)&l1[w][c];
    }
    if (he) {
        int o = t * 4;
        int w2 = o >> 6, c = o & 63;
        *(uint2*)(asc + (((size_t)(n * 16 + (h >> 1))) * 16 + w2) * 64 + c) = *(uint2*)&l2[w2][c];
    }
}

// Implicit-GEMM conv via MFMA 16x16x32 bf16.
// Tile: 128 co x 64 positions per block; 4 waves (2co x 2pos); K-step = 32.
// act: NHWC bf16 [N][HIN][HIN][CIN]; wq: packed [KSTEPS][128][32] bf16.
// MODE 0: epilogue bn2+actq4 -> a2out (NHWC bf16)
// MODE 1: write dout (fp32 NCHW)  -- shortcut
// MODE 2: dout += (read-add-write)
template <int CIN, int KSTEPS, int STRIDE, int PAD, int HIN, int MODE>
__global__ __launch_bounds__(256) void conv_mfma(const __bf16* __restrict__ act,
                                                 const __bf16* __restrict__ wq,
                                                 const float* __restrict__ sc2,
                                                 const float* __restrict__ sh2,
                                                 __bf16* __restrict__ a2out,
                                                 float* __restrict__ dout) {
    __shared__ __align__(16) __bf16 Alds[128][40];  // pad 32->40 (80B rows)
    __shared__ __align__(16) __bf16 Blds[64][40];
    const int t = threadIdx.x;
    const int wv = t >> 6, l = t & 63;
    const int wco = wv >> 1, wp = wv & 1;
    const int lrow = l & 15, half = l >> 4;
    const int pbase = blockIdx.x * 64;

    f32x4 acc[4][2] = {};

    // staging indices (B): thread t loads 8 bf16 for position posl, ci-chunk cio
    const int posl = t >> 2;
    const int cio = (t & 3) * 8;
    const int p = pbase + posl;
    const int n = p >> 8;
    const int rem = p & 255;
    const int h2 = rem >> 4, w2 = rem & 15;

    for (int s = 0; s < KSTEPS; ++s) {
        // stage A (weights): 4096 bf16 contiguous
        {
            const __bf16* src = wq + (size_t)s * 4096;
#pragma unroll
            for (int r = 0; r < 2; ++r) {
                int o = (r * 256 + t) * 8;
                int co = o >> 5, kk = o & 31;
                *(uint4*)&Alds[co][kk] = *(const uint4*)(src + o);
            }
        }
        // stage B (activations gather)
        {
            constexpr int CPS = CIN / 32;       // ci-chunks per (kh,kw)
            int khw = s / CPS;
            int ci0 = (s % CPS) * 32;
            int kh = khw / 3, kw = khw % 3;     // KHW==1 => khw==0 => kh=kw=0
            int hi = STRIDE * h2 + kh - PAD;
            int wi = STRIDE * w2 + kw - PAD;
            uint4 v = {0u, 0u, 0u, 0u};
            if (hi >= 0 && hi < HIN && wi >= 0 && wi < HIN)
                v = *(const uint4*)(act + (((size_t)(n * HIN + hi) * HIN + wi) * CIN + ci0 + cio));
            *(uint4*)&Blds[posl][cio] = v;
        }
        __syncthreads();
        bf16x8 a[4], b[2];
#pragma unroll
        for (int i = 0; i < 4; ++i)
            a[i] = *(const bf16x8*)&Alds[wco * 64 + i * 16 + lrow][half * 8];
#pragma unroll
        for (int j = 0; j < 2; ++j)
            b[j] = *(const bf16x8*)&Blds[wp * 32 + j * 16 + lrow][half * 8];
#pragma unroll
        for (int i = 0; i < 4; ++i)
#pragma unroll
            for (int j = 0; j < 2; ++j)
                acc[i][j] = __builtin_amdgcn_mfma_f32_16x16x32_bf16(a[i], b[j], acc[i][j], 0, 0, 0);
        __syncthreads();
    }

    // epilogue: C/D layout col=lane&15 (pos), row=(lane>>4)*4+reg (co)
#pragma unroll
    for (int i = 0; i < 4; ++i) {
#pragma unroll
        for (int j = 0; j < 2; ++j) {
            int pp = pbase + wp * 32 + j * 16 + lrow;
            int nn = pp >> 8;
            int rr = pp & 255;                   // h2*16 + w2
            int co0 = wco * 64 + i * 16 + half * 4;
            if constexpr (MODE == 0) {
                __bf16 tmp[4];
#pragma unroll
                for (int r = 0; r < 4; ++r) {
                    int co = co0 + r;
                    float v = acc[i][j][r] * sc2[co] + sh2[co];
                    float q = rintf(fminf(fmaxf(v, 0.f), 1.f) * 15.f) * (1.f / 15.f);
                    tmp[r] = (__bf16)q;
                }
                *(uint2*)(a2out + ((size_t)(nn * 256 + rr)) * 128 + co0) = *(uint2*)tmp;
            } else {
#pragma unroll
                for (int r = 0; r < 4; ++r) {
                    int co = co0 + r;
                    size_t oidx = ((size_t)nn * 128 + co) * 256 + rr;
                    float v = acc[i][j][r];
                    if constexpr (MODE == 2) v += dout[oidx];
                    dout[oidx] = v;
                }
            }
        }
    }
}

extern "C" void kernel_launch(void* const* d_in, const int* in_sizes, int n_in,
                              void* d_out, int out_size, void* d_ws, size_t ws_size,
                              hipStream_t stream) {
    const float* x   = (const float*)d_in[0];
    const float* w1  = (const float*)d_in[1];
    const float* w2  = (const float*)d_in[2];
    const float* wsw = (const float*)d_in[3];
    const float* g1  = (const float*)d_in[4];
    const float* b1  = (const float*)d_in[5];
    const float* m1  = (const float*)d_in[6];
    const float* v1  = (const float*)d_in[7];
    const float* g2  = (const float*)d_in[8];
    const float* b2  = (const float*)d_in[9];
    const float* m2  = (const float*)d_in[10];
    const float* v2  = (const float*)d_in[11];
    const float* gs  = (const float*)d_in[12];
    const float* bs  = (const float*)d_in[13];
    const float* ms  = (const float*)d_in[14];
    const float* vs  = (const float*)d_in[15];
    float* out = (float*)d_out;
    char* ws = (char*)d_ws;

    // ws layout (bytes), total ~56.4 MB
    __bf16* a1  = (__bf16*)(ws);                  // 256*32*32*64 bf16 = 32 MiB
    __bf16* a2  = (__bf16*)(ws + 33554432);       // 256*16*16*128 bf16 = 16 MiB
    __bf16* asc = (__bf16*)(ws + 50331648);       // 256*16*16*64 bf16 = 8 MiB
    __bf16* w1q = (__bf16*)(ws + 58720256);       // 18*128*32 bf16
    __bf16* w2q = (__bf16*)(ws + 58867712);       // 36*128*32 bf16
    __bf16* wsq = (__bf16*)(ws + 59162624);       // 2*128*32 bf16
    float*  bnp = (float*)(ws + 59179008);        // 512 floats
    float* wmax = (float*)(ws + 59181056);        // 2 floats

    k_init<<<1, 64, 0, stream>>>(wmax);
    k_wmax<<<64, 256, 0, stream>>>(w1, w2, wmax);
    k_bnprep<<<1, 128, 0, stream>>>(g1, b1, m1, v1, g2, b2, m2, v2, gs, bs, ms, vs, bnp);
    k_wq<64, 9, true><<<288, 256, 0, stream>>>(w1, w1q, wmax, 73728);
    k_wq<128, 9, true><<<576, 256, 0, stream>>>(w2, w2q, wmax + 1, 147456);
    k_wq<64, 1, false><<<32, 256, 0, stream>>>(wsw, wsq, nullptr, 8192);
    k_a1<<<8192, 256, 0, stream>>>(x, bnp, a1, asc);
    // shortcut: 1x1 over compacted bn_s(x), K=64
    conv_mfma<64, 2, 1, 0, 16, 1><<<1024, 256, 0, stream>>>(asc, wsq, nullptr, nullptr, nullptr, out);
    // conv1: 3x3 stride 2 pad 1, K=576; epilogue bn2+actq4 -> a2
    conv_mfma<64, 18, 2, 1, 32, 0><<<1024, 256, 0, stream>>>(a1, w1q, bnp + 256, bnp + 384, a2, nullptr);
    // conv2: 3x3 stride 1 pad 1, K=1152; epilogue adds shortcut from d_out
    conv_mfma<128, 36, 1, 1, 16, 2><<<1024, 256, 0, stream>>>(a2, w2q, nullptr, nullptr, nullptr, out);
}

// Round 5
// 106.933 us; speedup vs baseline: 1.3210x; 1.3210x over previous
//
#include <hip/hip_runtime.h>
#include <hip/hip_bf16.h>

// Wide_BasicBlock_Q: DoReFa-quantized residual block on MI355X (gfx950).
// Round 4: m97-structure convs (128x128 tile, global_load_lds w=16, 16 MFMA/
// wave/step), shortcut fused into conv2's K-loop (2 extra K-steps), OOB
// gather lanes redirected to a zero buffer (per-lane global addr, linear LDS).

typedef __bf16 bf16x8 __attribute__((ext_vector_type(8)));
typedef float f32x4 __attribute__((ext_vector_type(4)));

#define EPSV 1e-5f

__device__ __forceinline__ void gload16(const __bf16* g, __bf16* l) {
    __builtin_amdgcn_global_load_lds(
        (const __attribute__((address_space(1))) void*)g,
        (__attribute__((address_space(3))) void*)l, 16, 0, 0);
}

__global__ void k_init(float* wmax, uint4* zb) {
    if (threadIdx.x < 2) wmax[threadIdx.x] = 0.f;
    if (threadIdx.x < 4) zb[threadIdx.x] = uint4{0u, 0u, 0u, 0u};
}

__global__ __launch_bounds__(256) void k_wmax(const float* __restrict__ w1,
                                              const float* __restrict__ w2,
                                              float* wmax) {
    int sel = blockIdx.x >> 5;                 // 0: w1, 1: w2
    const float* src = sel ? w2 : w1;
    int cnt = sel ? 128 * 128 * 9 : 128 * 64 * 9;
    float m = 0.f;
    for (int i = (blockIdx.x & 31) * 256 + threadIdx.x; i < cnt; i += 32 * 256)
        m = fmaxf(m, fabsf(tanhf(src[i])));
#pragma unroll
    for (int off = 32; off > 0; off >>= 1)
        m = fmaxf(m, __shfl_down(m, off));
    __shared__ float red[4];
    if ((threadIdx.x & 63) == 0) red[threadIdx.x >> 6] = m;
    __syncthreads();
    if (threadIdx.x == 0) {
        m = fmaxf(fmaxf(red[0], red[1]), fmaxf(red[2], red[3]));
        atomicMax((int*)(wmax + sel), __float_as_int(m));  // all values >= 0
    }
}

// bnp layout (floats): [0:64)=sc1 [64:128)=sh1 [128:192)=scs [192:256)=shs
//                      [256:384)=sc2 [384:512)=sh2
__global__ void k_bnprep(const float* g1, const float* b1, const float* m1, const float* v1,
                         const float* g2, const float* b2, const float* m2, const float* v2,
                         const float* gs, const float* bs, const float* ms, const float* vs,
                         float* bnp) {
    int c = threadIdx.x;  // blockDim = 128
    if (c < 64) {
        float s = g1[c] * rsqrtf(v1[c] + EPSV);
        bnp[c] = s;          bnp[64 + c] = b1[c] - m1[c] * s;
        float s2 = gs[c] * rsqrtf(vs[c] + EPSV);
        bnp[128 + c] = s2;   bnp[192 + c] = bs[c] - ms[c] * s2;
    }
    float s = g2[c] * rsqrtf(v2[c] + EPSV);
    bnp[256 + c] = s;        bnp[384 + c] = b2[c] - m2[c] * s;
}

// Quantize (DoReFa) + prepack weights: dst[((s*128 + co)*32 + kk)] with
// k = s*32+kk, k-order = khw*CIN + ci, src layout [co][ci][kh][kw].
template <int CIN, int KHW, bool QUANT>
__global__ __launch_bounds__(256) void k_wq(const float* __restrict__ w,
                                            __bf16* __restrict__ dst,
                                            const float* __restrict__ wmax, int total) {
    int idx = blockIdx.x * 256 + threadIdx.x;
    if (idx >= total) return;
    int kk = idx & 31;
    int co = (idx >> 5) & 127;
    int s = idx >> 12;
    int k = s * 32 + kk;
    int khw = k / CIN;
    int ci = k % CIN;
    float v = w[(co * CIN + ci) * KHW + khw];
    float outv;
    if constexpr (QUANT) {
        float M = *wmax;
        float t = tanhf(v) / (2.f * M) + 0.5f;          // in [0,1]
        outv = 2.f * (rintf(t * 15.f) * (1.f / 15.f)) - 1.f;
    } else {
        outv = v;
    }
    dst[idx] = (__bf16)outv;
}

// a1 = actq4(bn1(x)) -> NHWC bf16 [256][32][32][64]
// asc = bn_s(x) at even (h,w) -> NHWC bf16 [256][16][16][64]
__global__ __launch_bounds__(256) void k_a1(const float* __restrict__ x,
                                            const float* __restrict__ bnp,
                                            __bf16* __restrict__ a1,
                                            __bf16* __restrict__ asc) {
    __shared__ __align__(16) __bf16 l1[32][72];
    __shared__ __align__(16) __bf16 l2[16][72];
    __shared__ float s1[64], h1[64], ss[64], hs[64];
    int t = threadIdx.x;
    int n = blockIdx.x >> 5, h = blockIdx.x & 31;
    if (t < 64) {
        s1[t] = bnp[t];       h1[t] = bnp[64 + t];
        ss[t] = bnp[128 + t]; hs[t] = bnp[192 + t];
    }
    __syncthreads();
    bool he = (h & 1) == 0;
#pragma unroll
    for (int i = 0; i < 8; ++i) {
        int idx = t + i * 256;          // over (c,w): c=idx>>5, w=idx&31
        int c = idx >> 5, w = idx & 31;
        float xv = x[((n * 64 + c) * 32 + h) * 32 + w];
        float v = xv * s1[c] + h1[c];
        float q = rintf(fminf(fmaxf(v, 0.f), 1.f) * 15.f) * (1.f / 15.f);
        l1[w][c] = (__bf16)q;
        if (he && !(w & 1)) l2[w >> 1][c] = (__bf16)(xv * ss[c] + hs[c]);
    }
    __syncthreads();
    {
        int o = t * 8;                  // over (w,c): w=o>>6, c=o&63
        int w = o >> 6, c = o & 63;
        *(uint4*)(a1 + (((size_t)(n * 32 + h)) * 32 + w) * 64 + c) = *(uint4*)&l1[w][c];
    }
    if (he) {
        int o = t * 4;
        int w2 = o >> 6, c = o & 63;
        *(uint2*)(asc + (((size_t)(n * 16 + (h >> 1))) * 16 + w2) * 64 + c) = *(uint2*)&l2[w2][c];
    }
}

// Implicit-GEMM conv via MFMA 16x16x32 bf16 — m97 structure.
// Tile: 128 co x 128 positions; 4 waves (2co x 2pos), each 64x64 (acc 4x4).
// K-step 32; A/B staged with global_load_lds dwordx4 into linear LDS [128][32].
// OOB gather lanes read a 16B zero buffer (per-lane global address).
// Optional fused shortcut tail: KS_SC extra K-steps gathering from actsc
// (NHWC [N][16][16][64], 1x1, no pad), weights appended in wq.
// MODE 0: epilogue bn2+actq4 -> a2out (NHWC bf16 [N][16][16][128])
// MODE 1: write dout (fp32 NCHW)
template <int CIN, int KS_MAIN, int KS_SC, int STRIDE, int HIN, int MODE>
__global__ __launch_bounds__(256) void conv_mfma(
        const __bf16* __restrict__ act, const __bf16* __restrict__ actsc,
        const __bf16* __restrict__ wq,
        const float* __restrict__ sc2, const float* __restrict__ sh2,
        const __bf16* __restrict__ zerob,
        __bf16* __restrict__ a2out, float* __restrict__ dout) {
    __shared__ __align__(16) __bf16 Alds[128][32];   // [co][k]
    __shared__ __align__(16) __bf16 Blds[128][32];   // [pos][k]
    const int t = threadIdx.x;
    const int wv = t >> 6, l = t & 63;
    const int wco = wv >> 1, wp = wv & 1;
    const int lrow = l & 15, half = l >> 4;
    const int pbase = blockIdx.x * 128;
    const int n = pbase >> 8;            // wave-uniform: block covers half an image
    const int rbase = pbase & 255;       // 0 or 128

    f32x4 acc[4][4] = {};

    // B staging geometry: thread t stages 16B chunks t and 256+t.
    // chunk c: posl = c>>2 (row, 0..127), sub-chunk = c&3 (8 bf16 of the 32-k slab)
    const int sub = (t & 3) * 8;
    const int pl = t >> 2;               // 0..63 (r=0); r=1 adds 64 -> +4 h-rows
    const int w2 = pl & 15;
    const int h20 = (rbase >> 4) + (pl >> 4);
    const int hi0b = STRIDE * h20 - 1;   // + kh
    const int hi1b = hi0b + 4 * STRIDE;  // position +64 => h2+4
    const int wib  = STRIDE * w2 - 1;    // + kw

    __bf16* lA = &Alds[0][0] + wv * 512;  // wave-uniform LDS base (64 chunks)
    __bf16* lB = &Blds[0][0] + wv * 512;

    constexpr int CPS = CIN / 32;         // ci-chunks per (kh,kw)
    constexpr int KS = KS_MAIN + KS_SC;
    for (int s = 0; s < KS; ++s) {
        // stage A (weights, fully linear)
        const __bf16* gA = wq + (size_t)s * 4096 + t * 8;
        gload16(gA, lA);
        gload16(gA + 2048, lA + 2048);
        // stage B (activation gather)
        if (KS_SC == 0 || s < KS_MAIN) {
            int khw = s / CPS;
            int ci0 = (s % CPS) * 32;
            int kh = khw / 3, kw = khw - kh * 3;   // 1x1 conv never takes this path here
            int hi0 = hi0b + kh, hi1 = hi1b + kh, wi = wib + kw;
            bool okw = (unsigned)wi < (unsigned)HIN;
            const __bf16* g0 = (okw && (unsigned)hi0 < (unsigned)HIN)
                ? act + ((size_t)(n * HIN + hi0) * HIN + wi) * CIN + ci0 + sub : zerob;
            const __bf16* g1 = (okw && (unsigned)hi1 < (unsigned)HIN)
                ? act + ((size_t)(n * HIN + hi1) * HIN + wi) * CIN + ci0 + sub : zerob;
            gload16(g0, lB);
            gload16(g1, lB + 2048);
        } else {
            int ci0 = (s - KS_MAIN) * 32;
            const __bf16* g0 = actsc + ((size_t)(n * 16 + h20) * 16 + w2) * 64 + ci0 + sub;
            gload16(g0, lB);
            gload16(g0 + 4096, lB + 2048);   // +4 rows * 16 * 64
        }
        __syncthreads();                      // drains vmcnt: DMA landed
        bf16x8 af[4], bfr[4];
#pragma unroll
        for (int i = 0; i < 4; ++i)
            af[i] = *(const bf16x8*)&Alds[wco * 64 + i * 16 + lrow][half * 8];
#pragma unroll
        for (int j = 0; j < 4; ++j)
            bfr[j] = *(const bf16x8*)&Blds[wp * 64 + j * 16 + lrow][half * 8];
#pragma unroll
        for (int i = 0; i < 4; ++i)
#pragma unroll
            for (int j = 0; j < 4; ++j)
                acc[i][j] = __builtin_amdgcn_mfma_f32_16x16x32_bf16(af[i], bfr[j], acc[i][j], 0, 0, 0);
        __syncthreads();                      // all reads done before next DMA
    }

    // epilogue: C/D layout col=lane&15 (pos), row=(lane>>4)*4+reg (co)
#pragma unroll
    for (int i = 0; i < 4; ++i) {
        const int co0 = wco * 64 + i * 16 + half * 4;
        float s2[4], h2v[4];
        if constexpr (MODE == 0) {
#pragma unroll
            for (int r = 0; r < 4; ++r) { s2[r] = sc2[co0 + r]; h2v[r] = sh2[co0 + r]; }
        }
#pragma unroll
        for (int j = 0; j < 4; ++j) {
            const int rr = rbase + wp * 64 + j * 16 + lrow;
            if constexpr (MODE == 0) {
                __bf16 tmp[4];
#pragma unroll
                for (int r = 0; r < 4; ++r) {
                    float v = acc[i][j][r] * s2[r] + h2v[r];
                    tmp[r] = (__bf16)(rintf(fminf(fmaxf(v, 0.f), 1.f) * 15.f) * (1.f / 15.f));
                }
                *(uint2*)(a2out + ((size_t)n * 256 + rr) * 128 + co0) = *(uint2*)tmp;
            } else {
#pragma unroll
                for (int r = 0; r < 4; ++r)
                    dout[((size_t)n * 128 + co0 + r) * 256 + rr] = acc[i][j][r];
            }
        }
    }
}

extern "C" void kernel_launch(void* const* d_in, const int* in_sizes, int n_in,
                              void* d_out, int out_size, void* d_ws, size_t ws_size,
                              hipStream_t stream) {
    const float* x   = (const float*)d_in[0];
    const float* w1  = (const float*)d_in[1];
    const float* w2  = (const float*)d_in[2];
    const float* wsw = (const float*)d_in[3];
    const float* g1  = (const float*)d_in[4];
    const float* b1  = (const float*)d_in[5];
    const float* m1  = (const float*)d_in[6];
    const float* v1  = (const float*)d_in[7];
    const float* g2  = (const float*)d_in[8];
    const float* b2  = (const float*)d_in[9];
    const float* m2  = (const float*)d_in[10];
    const float* v2  = (const float*)d_in[11];
    const float* gs  = (const float*)d_in[12];
    const float* bs  = (const float*)d_in[13];
    const float* ms  = (const float*)d_in[14];
    const float* vs  = (const float*)d_in[15];
    float* out = (float*)d_out;
    char* ws = (char*)d_ws;

    // ws layout (bytes), total 59,181,128
    __bf16* zerob = (__bf16*)(ws);                      // 64 B zeros
    __bf16* a1  = (__bf16*)(ws + 64);                   // 256*32*32*64 bf16 = 32 MiB
    __bf16* a2  = (__bf16*)(ws + 64 + 33554432);        // 256*16*16*128 bf16 = 16 MiB
    __bf16* asc = (__bf16*)(ws + 64 + 50331648);        // 256*16*16*64 bf16 = 8 MiB
    __bf16* w1q = (__bf16*)(ws + 64 + 58720256);        // 18*128*32 bf16
    __bf16* w2q = (__bf16*)(ws + 64 + 58867712);        // 38*128*32 bf16 (w2 + ws tail)
    float*  bnp = (float*)(ws + 64 + 59179008);         // 512 floats
    float* wmax = (float*)(ws + 64 + 59181056);         // 2 floats

    k_init<<<1, 64, 0, stream>>>(wmax, (uint4*)zerob);
    k_wmax<<<64, 256, 0, stream>>>(w1, w2, wmax);
    k_bnprep<<<1, 128, 0, stream>>>(g1, b1, m1, v1, g2, b2, m2, v2, gs, bs, ms, vs, bnp);
    k_wq<64, 9, true><<<288, 256, 0, stream>>>(w1, w1q, wmax, 73728);
    k_wq<128, 9, true><<<576, 256, 0, stream>>>(w2, w2q, wmax + 1, 147456);
    k_wq<64, 1, false><<<32, 256, 0, stream>>>(wsw, w2q + 36 * 4096, nullptr, 8192);
    k_a1<<<8192, 256, 0, stream>>>(x, bnp, a1, asc);
    // conv1: 3x3 stride 2 pad 1 on a1 (K=576); epilogue bn2+actq4 -> a2
    conv_mfma<64, 18, 0, 2, 32, 0><<<512, 256, 0, stream>>>(
        a1, nullptr, w1q, bnp + 256, bnp + 384, zerob, a2, nullptr);
    // conv2: 3x3 stride 1 pad 1 on a2 (K=1152) + fused 1x1 shortcut (K=64) -> out
    conv_mfma<128, 36, 2, 1, 16, 1><<<512, 256, 0, stream>>>(
        a2, asc, w2q, nullptr, nullptr, zerob, nullptr, out);
}

// Round 6
// 104.857 us; speedup vs baseline: 1.3472x; 1.0198x over previous
//
#include <hip/hip_runtime.h>
#include <hip/hip_bf16.h>

// Wide_BasicBlock_Q: DoReFa-quantized residual block on MI355X (gfx950).
// Round 5: conv K-loop double-buffered (T3 minimum 2-phase: prefetch next
// K-step via global_load_lds BEFORE compute, single __syncthreads per step).
// k_wmax computes max|w| (tanh applied once in k_wq — monotonicity).
// k_a1 uses float4 loads.

typedef __bf16 bf16x8 __attribute__((ext_vector_type(8)));
typedef float f32x4 __attribute__((ext_vector_type(4)));

#define EPSV 1e-5f

__device__ __forceinline__ void gload16(const __bf16* g, __bf16* l) {
    __builtin_amdgcn_global_load_lds(
        (const __attribute__((address_space(1))) void*)g,
        (__attribute__((address_space(3))) void*)l, 16, 0, 0);
}

__global__ void k_init(float* wmax, uint4* zb) {
    if (threadIdx.x < 2) wmax[threadIdx.x] = 0.f;
    if (threadIdx.x < 4) zb[threadIdx.x] = uint4{0u, 0u, 0u, 0u};
}

// max|w| per tensor (tanh is monotonic: max|tanh(w)| = tanh(max|w|))
__global__ __launch_bounds__(256) void k_wmax(const float* __restrict__ w1,
                                              const float* __restrict__ w2,
                                              float* wmax) {
    int sel = blockIdx.x >> 4;                 // 0: w1, 1: w2
    const float* src = sel ? w2 : w1;
    int cnt = sel ? 128 * 128 * 9 : 128 * 64 * 9;
    float m = 0.f;
    for (int i = (blockIdx.x & 15) * 256 + threadIdx.x; i < cnt; i += 16 * 256)
        m = fmaxf(m, fabsf(src[i]));
#pragma unroll
    for (int off = 32; off > 0; off >>= 1)
        m = fmaxf(m, __shfl_down(m, off));
    __shared__ float red[4];
    if ((threadIdx.x & 63) == 0) red[threadIdx.x >> 6] = m;
    __syncthreads();
    if (threadIdx.x == 0) {
        m = fmaxf(fmaxf(red[0], red[1]), fmaxf(red[2], red[3]));
        atomicMax((int*)(wmax + sel), __float_as_int(m));  // all values >= 0
    }
}

// bnp layout (floats): [0:64)=sc1 [64:128)=sh1 [128:192)=scs [192:256)=shs
//                      [256:384)=sc2 [384:512)=sh2
__global__ void k_bnprep(const float* g1, const float* b1, const float* m1, const float* v1,
                         const float* g2, const float* b2, const float* m2, const float* v2,
                         const float* gs, const float* bs, const float* ms, const float* vs,
                         float* bnp) {
    int c = threadIdx.x;  // blockDim = 128
    if (c < 64) {
        float s = g1[c] * rsqrtf(v1[c] + EPSV);
        bnp[c] = s;          bnp[64 + c] = b1[c] - m1[c] * s;
        float s2 = gs[c] * rsqrtf(vs[c] + EPSV);
        bnp[128 + c] = s2;   bnp[192 + c] = bs[c] - ms[c] * s2;
    }
    float s = g2[c] * rsqrtf(v2[c] + EPSV);
    bnp[256 + c] = s;        bnp[384 + c] = b2[c] - m2[c] * s;
}

// Quantize (DoReFa) + prepack weights: dst[((s*128 + co)*32 + kk)] with
// k = s*32+kk, k-order = khw*CIN + ci, src layout [co][ci][kh][kw].
template <int CIN, int KHW, bool QUANT>
__global__ __launch_bounds__(256) void k_wq(const float* __restrict__ w,
                                            __bf16* __restrict__ dst,
                                            const float* __restrict__ wmax, int total) {
    int idx = blockIdx.x * 256 + threadIdx.x;
    if (idx >= total) return;
    int kk = idx & 31;
    int co = (idx >> 5) & 127;
    int s = idx >> 12;
    int k = s * 32 + kk;
    int khw = k / CIN;
    int ci = k % CIN;
    float v = w[(co * CIN + ci) * KHW + khw];
    float outv;
    if constexpr (QUANT) {
        float M = tanhf(*wmax);                          // max|tanh(w)|
        float t = tanhf(v) / (2.f * M) + 0.5f;           // in [0,1]
        outv = 2.f * (rintf(t * 15.f) * (1.f / 15.f)) - 1.f;
    } else {
        outv = v;
    }
    dst[idx] = (__bf16)outv;
}

// a1 = actq4(bn1(x)) -> NHWC bf16 [256][32][32][64]
// asc = bn_s(x) at even (h,w) -> NHWC bf16 [256][16][16][64]
__global__ __launch_bounds__(256) void k_a1(const float* __restrict__ x,
                                            const float* __restrict__ bnp,
                                            __bf16* __restrict__ a1,
                                            __bf16* __restrict__ asc) {
    __shared__ __align__(16) __bf16 l1[32][72];
    __shared__ __align__(16) __bf16 l2[16][72];
    __shared__ float s1[64], h1[64], ss[64], hs[64];
    int t = threadIdx.x;
    int n = blockIdx.x >> 5, h = blockIdx.x & 31;
    if (t < 64) {
        s1[t] = bnp[t];       h1[t] = bnp[64 + t];
        ss[t] = bnp[128 + t]; hs[t] = bnp[192 + t];
    }
    __syncthreads();
    bool he = (h & 1) == 0;
#pragma unroll
    for (int i = 0; i < 2; ++i) {
        int idx = t + i * 256;          // over (c,w4): c=idx>>3, w0=(idx&7)*4
        int c = idx >> 3, w0 = (idx & 7) * 4;
        float4 xv = *(const float4*)(x + (((size_t)(n * 64 + c) * 32 + h) * 32 + w0));
        float xa[4] = {xv.x, xv.y, xv.z, xv.w};
#pragma unroll
        for (int k = 0; k < 4; ++k) {
            float v = xa[k] * s1[c] + h1[c];
            float q = rintf(fminf(fmaxf(v, 0.f), 1.f) * 15.f) * (1.f / 15.f);
            l1[w0 + k][c] = (__bf16)q;
        }
        if (he) {
            l2[w0 >> 1][c]       = (__bf16)(xa[0] * ss[c] + hs[c]);
            l2[(w0 >> 1) + 1][c] = (__bf16)(xa[2] * ss[c] + hs[c]);
        }
    }
    __syncthreads();
    {
        int o = t * 8;                  // over (w,c): w=o>>6, c=o&63
        int w = o >> 6, c = o & 63;
        *(uint4*)(a1 + (((size_t)(n * 32 + h)) * 32 + w) * 64 + c) = *(uint4*)&l1[w][c];
    }
    if (he) {
        int o = t * 4;
        int w2 = o >> 6, c = o & 63;
        *(uint2*)(asc + (((size_t)(n * 16 + (h >> 1))) * 16 + w2) * 64 + c) = *(uint2*)&l2[w2][c];
    }
}

// Implicit-GEMM conv via MFMA 16x16x32 bf16 — m97 structure + 2-phase dbuf.
// Tile: 128 co x 128 positions; 4 waves (2co x 2pos), each 64x64 (acc 4x4).
// K-step 32; A/B staged with global_load_lds dwordx4 into linear LDS [128][32],
// double-buffered: prefetch step s+1 issued BEFORE compute of step s; the
// __syncthreads() at step end drains vmcnt (prefetch latency hidden by MFMA).
// OOB gather lanes read a 16B zero buffer (per-lane global address).
// Fused shortcut tail: KS_SC extra K-steps gathering from actsc
// (NHWC [N][16][16][64], 1x1, no pad), weights appended in wq.
// MODE 0: epilogue bn2+actq4 -> a2out (NHWC bf16 [N][16][16][128])
// MODE 1: write dout (fp32 NCHW)
template <int CIN, int KS_MAIN, int KS_SC, int STRIDE, int HIN, int MODE>
__global__ __launch_bounds__(256) void conv_mfma(
        const __bf16* __restrict__ act, const __bf16* __restrict__ actsc,
        const __bf16* __restrict__ wq,
        const float* __restrict__ sc2, const float* __restrict__ sh2,
        const __bf16* __restrict__ zerob,
        __bf16* __restrict__ a2out, float* __restrict__ dout) {
    __shared__ __align__(16) __bf16 Alds[2][128][32];   // [buf][co][k]
    __shared__ __align__(16) __bf16 Blds[2][128][32];   // [buf][pos][k]
    const int t = threadIdx.x;
    const int wv = t >> 6, l = t & 63;
    const int wco = wv >> 1, wp = wv & 1;
    const int lrow = l & 15, half = l >> 4;
    const int pbase = blockIdx.x * 128;
    const int n = pbase >> 8;            // wave-uniform: block covers half an image
    const int rbase = pbase & 255;       // 0 or 128

    f32x4 acc[4][4] = {};

    // B staging geometry: thread t stages 16B chunks t and 256+t.
    // chunk c: posl = c>>2 (row), sub-chunk = c&3 (8 bf16 of the 32-k slab)
    const int sub = (t & 3) * 8;
    const int pl = t >> 2;               // 0..63; chunk 256+t adds 64 -> +4 h-rows
    const int w2 = pl & 15;
    const int h20 = (rbase >> 4) + (pl >> 4);
    const int hi0b = STRIDE * h20 - 1;   // + kh
    const int hi1b = hi0b + 4 * STRIDE;  // position +64 => h2+4
    const int wib  = STRIDE * w2 - 1;    // + kw

    constexpr int CPS = CIN / 32;        // ci-chunks per (kh,kw)
    constexpr int KS = KS_MAIN + KS_SC;

    auto stage = [&](int s, int pg) {
        // A (weights, fully linear)
        const __bf16* gA = wq + (size_t)s * 4096 + t * 8;
        __bf16* lA = &Alds[pg][0][0] + wv * 512;
        gload16(gA, lA);
        gload16(gA + 2048, lA + 2048);
        // B (activation gather)
        __bf16* lB = &Blds[pg][0][0] + wv * 512;
        if (KS_SC == 0 || s < KS_MAIN) {
            int khw = s / CPS;
            int ci0 = (s % CPS) * 32;
            int kh = khw / 3, kw = khw - kh * 3;
            int hi0 = hi0b + kh, hi1 = hi1b + kh, wi = wib + kw;
            bool okw = (unsigned)wi < (unsigned)HIN;
            const __bf16* g0 = (okw && (unsigned)hi0 < (unsigned)HIN)
                ? act + ((size_t)(n * HIN + hi0) * HIN + wi) * CIN + ci0 + sub : zerob;
            const __bf16* g1 = (okw && (unsigned)hi1 < (unsigned)HIN)
                ? act + ((size_t)(n * HIN + hi1) * HIN + wi) * CIN + ci0 + sub : zerob;
            gload16(g0, lB);
            gload16(g1, lB + 2048);
        } else {
            int ci0 = (s - KS_MAIN) * 32;
            const __bf16* g0 = actsc + ((size_t)(n * 16 + h20) * 16 + w2) * 64 + ci0 + sub;
            gload16(g0, lB);
            gload16(g0 + 4096, lB + 2048);   // +4 h-rows * 16 * 64
        }
    };

    stage(0, 0);
    __syncthreads();                         // prologue: buf0 ready
#pragma unroll 2
    for (int s = 0; s < KS; ++s) {
        const int cur = s & 1;
        if (s + 1 < KS) stage(s + 1, cur ^ 1);   // prefetch next K-step
        bf16x8 af[4], bfr[4];
#pragma unroll
        for (int i = 0; i < 4; ++i)
            af[i] = *(const bf16x8*)&Alds[cur][wco * 64 + i * 16 + lrow][half * 8];
#pragma unroll
        for (int j = 0; j < 4; ++j)
            bfr[j] = *(const bf16x8*)&Blds[cur][wp * 64 + j * 16 + lrow][half * 8];
#pragma unroll
        for (int i = 0; i < 4; ++i)
#pragma unroll
            for (int j = 0; j < 4; ++j)
                acc[i][j] = __builtin_amdgcn_mfma_f32_16x16x32_bf16(af[i], bfr[j], acc[i][j], 0, 0, 0);
        __syncthreads();                     // drains vmcnt: prefetch landed,
    }                                        // all reads of buf[cur] done

    // epilogue: C/D layout col=lane&15 (pos), row=(lane>>4)*4+reg (co)
#pragma unroll
    for (int i = 0; i < 4; ++i) {
        const int co0 = wco * 64 + i * 16 + half * 4;
        float s2[4], h2v[4];
        if constexpr (MODE == 0) {
#pragma unroll
            for (int r = 0; r < 4; ++r) { s2[r] = sc2[co0 + r]; h2v[r] = sh2[co0 + r]; }
        }
#pragma unroll
        for (int j = 0; j < 4; ++j) {
            const int rr = rbase + wp * 64 + j * 16 + lrow;
            if constexpr (MODE == 0) {
                __bf16 tmp[4];
#pragma unroll
                for (int r = 0; r < 4; ++r) {
                    float v = acc[i][j][r] * s2[r] + h2v[r];
                    tmp[r] = (__bf16)(rintf(fminf(fmaxf(v, 0.f), 1.f) * 15.f) * (1.f / 15.f));
                }
                *(uint2*)(a2out + ((size_t)n * 256 + rr) * 128 + co0) = *(uint2*)tmp;
            } else {
#pragma unroll
                for (int r = 0; r < 4; ++r)
                    dout[((size_t)n * 128 + co0 + r) * 256 + rr] = acc[i][j][r];
            }
        }
    }
}

extern "C" void kernel_launch(void* const* d_in, const int* in_sizes, int n_in,
                              void* d_out, int out_size, void* d_ws, size_t ws_size,
                              hipStream_t stream) {
    const float* x   = (const float*)d_in[0];
    const float* w1  = (const float*)d_in[1];
    const float* w2  = (const float*)d_in[2];
    const float* wsw = (const float*)d_in[3];
    const float* g1  = (const float*)d_in[4];
    const float* b1  = (const float*)d_in[5];
    const float* m1  = (const float*)d_in[6];
    const float* v1  = (const float*)d_in[7];
    const float* g2  = (const float*)d_in[8];
    const float* b2  = (const float*)d_in[9];
    const float* m2  = (const float*)d_in[10];
    const float* v2  = (const float*)d_in[11];
    const float* gs  = (const float*)d_in[12];
    const float* bs  = (const float*)d_in[13];
    const float* ms  = (const float*)d_in[14];
    const float* vs  = (const float*)d_in[15];
    float* out = (float*)d_out;
    char* ws = (char*)d_ws;

    // ws layout (bytes)
    __bf16* zerob = (__bf16*)(ws);                      // 64 B zeros
    __bf16* a1  = (__bf16*)(ws + 64);                   // 256*32*32*64 bf16 = 32 MiB
    __bf16* a2  = (__bf16*)(ws + 64 + 33554432);        // 256*16*16*128 bf16 = 16 MiB
    __bf16* asc = (__bf16*)(ws + 64 + 50331648);        // 256*16*16*64 bf16 = 8 MiB
    __bf16* w1q = (__bf16*)(ws + 64 + 58720256);        // 18*128*32 bf16
    __bf16* w2q = (__bf16*)(ws + 64 + 58867712);        // 38*128*32 bf16 (w2 + ws tail)
    float*  bnp = (float*)(ws + 64 + 59179008);         // 512 floats
    float* wmax = (float*)(ws + 64 + 59181056);         // 2 floats

    k_init<<<1, 64, 0, stream>>>(wmax, (uint4*)zerob);
    k_wmax<<<32, 256, 0, stream>>>(w1, w2, wmax);
    k_bnprep<<<1, 128, 0, stream>>>(g1, b1, m1, v1, g2, b2, m2, v2, gs, bs, ms, vs, bnp);
    k_wq<64, 9, true><<<288, 256, 0, stream>>>(w1, w1q, wmax, 73728);
    k_wq<128, 9, true><<<576, 256, 0, stream>>>(w2, w2q, wmax + 1, 147456);
    k_wq<64, 1, false><<<32, 256, 0, stream>>>(wsw, w2q + 36 * 4096, nullptr, 8192);
    k_a1<<<8192, 256, 0, stream>>>(x, bnp, a1, asc);
    // conv1: 3x3 stride 2 pad 1 on a1 (K=576); epilogue bn2+actq4 -> a2
    conv_mfma<64, 18, 0, 2, 32, 0><<<512, 256, 0, stream>>>(
        a1, nullptr, w1q, bnp + 256, bnp + 384, zerob, a2, nullptr);
    // conv2: 3x3 stride 1 pad 1 on a2 (K=1152) + fused 1x1 shortcut (K=64) -> out
    conv_mfma<128, 36, 2, 1, 16, 1><<<512, 256, 0, stream>>>(
        a2, asc, w2q, nullptr, nullptr, zerob, nullptr, out);
}

// Round 7
// 102.176 us; speedup vs baseline: 1.3825x; 1.0262x over previous
//
#include <hip/hip_runtime.h>
#include <hip/hip_bf16.h>

// Wide_BasicBlock_Q: DoReFa-quantized residual block on MI355X (gfx950).
// Round 6: conv K-loop -> 4-buffer LDS ring, 3-deep global_load_lds prefetch,
// counted s_waitcnt vmcnt(8) + raw s_barrier (T3+T4), s_setprio around MFMA
// cluster (T5). Loads never drain to 0 in the main loop (drain 8->4->0 tail).

typedef __bf16 bf16x8 __attribute__((ext_vector_type(8)));
typedef float f32x4 __attribute__((ext_vector_type(4)));

#define EPSV 1e-5f

__device__ __forceinline__ void gload16(const __bf16* g, __bf16* l) {
    __builtin_amdgcn_global_load_lds(
        (const __attribute__((address_space(1))) void*)g,
        (__attribute__((address_space(3))) void*)l, 16, 0, 0);
}

__global__ void k_init(float* wmax, uint4* zb) {
    if (threadIdx.x < 2) wmax[threadIdx.x] = 0.f;
    if (threadIdx.x < 4) zb[threadIdx.x] = uint4{0u, 0u, 0u, 0u};
}

// max|w| per tensor (tanh is monotonic: max|tanh(w)| = tanh(max|w|))
__global__ __launch_bounds__(256) void k_wmax(const float* __restrict__ w1,
                                              const float* __restrict__ w2,
                                              float* wmax) {
    int sel = blockIdx.x >> 4;                 // 0: w1, 1: w2
    const float* src = sel ? w2 : w1;
    int cnt = sel ? 128 * 128 * 9 : 128 * 64 * 9;
    float m = 0.f;
    for (int i = (blockIdx.x & 15) * 256 + threadIdx.x; i < cnt; i += 16 * 256)
        m = fmaxf(m, fabsf(src[i]));
#pragma unroll
    for (int off = 32; off > 0; off >>= 1)
        m = fmaxf(m, __shfl_down(m, off));
    __shared__ float red[4];
    if ((threadIdx.x & 63) == 0) red[threadIdx.x >> 6] = m;
    __syncthreads();
    if (threadIdx.x == 0) {
        m = fmaxf(fmaxf(red[0], red[1]), fmaxf(red[2], red[3]));
        atomicMax((int*)(wmax + sel), __float_as_int(m));  // all values >= 0
    }
}

// bnp layout (floats): [0:64)=sc1 [64:128)=sh1 [128:192)=scs [192:256)=shs
//                      [256:384)=sc2 [384:512)=sh2
__global__ void k_bnprep(const float* g1, const float* b1, const float* m1, const float* v1,
                         const float* g2, const float* b2, const float* m2, const float* v2,
                         const float* gs, const float* bs, const float* ms, const float* vs,
                         float* bnp) {
    int c = threadIdx.x;  // blockDim = 128
    if (c < 64) {
        float s = g1[c] * rsqrtf(v1[c] + EPSV);
        bnp[c] = s;          bnp[64 + c] = b1[c] - m1[c] * s;
        float s2 = gs[c] * rsqrtf(vs[c] + EPSV);
        bnp[128 + c] = s2;   bnp[192 + c] = bs[c] - ms[c] * s2;
    }
    float s = g2[c] * rsqrtf(v2[c] + EPSV);
    bnp[256 + c] = s;        bnp[384 + c] = b2[c] - m2[c] * s;
}

// Quantize (DoReFa) + prepack weights: dst[((s*128 + co)*32 + kk)] with
// k = s*32+kk, k-order = khw*CIN + ci, src layout [co][ci][kh][kw].
template <int CIN, int KHW, bool QUANT>
__global__ __launch_bounds__(256) void k_wq(const float* __restrict__ w,
                                            __bf16* __restrict__ dst,
                                            const float* __restrict__ wmax, int total) {
    int idx = blockIdx.x * 256 + threadIdx.x;
    if (idx >= total) return;
    int kk = idx & 31;
    int co = (idx >> 5) & 127;
    int s = idx >> 12;
    int k = s * 32 + kk;
    int khw = k / CIN;
    int ci = k % CIN;
    float v = w[(co * CIN + ci) * KHW + khw];
    float outv;
    if constexpr (QUANT) {
        float M = tanhf(*wmax);                          // max|tanh(w)|
        float t = tanhf(v) / (2.f * M) + 0.5f;           // in [0,1]
        outv = 2.f * (rintf(t * 15.f) * (1.f / 15.f)) - 1.f;
    } else {
        outv = v;
    }
    dst[idx] = (__bf16)outv;
}

// a1 = actq4(bn1(x)) -> NHWC bf16 [256][32][32][64]
// asc = bn_s(x) at even (h,w) -> NHWC bf16 [256][16][16][64]
__global__ __launch_bounds__(256) void k_a1(const float* __restrict__ x,
                                            const float* __restrict__ bnp,
                                            __bf16* __restrict__ a1,
                                            __bf16* __restrict__ asc) {
    __shared__ __align__(16) __bf16 l1[32][72];
    __shared__ __align__(16) __bf16 l2[16][72];
    __shared__ float s1[64], h1[64], ss[64], hs[64];
    int t = threadIdx.x;
    int n = blockIdx.x >> 5, h = blockIdx.x & 31;
    if (t < 64) {
        s1[t] = bnp[t];       h1[t] = bnp[64 + t];
        ss[t] = bnp[128 + t]; hs[t] = bnp[192 + t];
    }
    __syncthreads();
    bool he = (h & 1) == 0;
#pragma unroll
    for (int i = 0; i < 2; ++i) {
        int idx = t + i * 256;          // over (c,w4): c=idx>>3, w0=(idx&7)*4
        int c = idx >> 3, w0 = (idx & 7) * 4;
        float4 xv = *(const float4*)(x + (((size_t)(n * 64 + c) * 32 + h) * 32 + w0));
        float xa[4] = {xv.x, xv.y, xv.z, xv.w};
#pragma unroll
        for (int k = 0; k < 4; ++k) {
            float v = xa[k] * s1[c] + h1[c];
            float q = rintf(fminf(fmaxf(v, 0.f), 1.f) * 15.f) * (1.f / 15.f);
            l1[w0 + k][c] = (__bf16)q;
        }
        if (he) {
            l2[w0 >> 1][c]       = (__bf16)(xa[0] * ss[c] + hs[c]);
            l2[(w0 >> 1) + 1][c] = (__bf16)(xa[2] * ss[c] + hs[c]);
        }
    }
    __syncthreads();
    {
        int o = t * 8;                  // over (w,c): w=o>>6, c=o&63
        int w = o >> 6, c = o & 63;
        *(uint4*)(a1 + (((size_t)(n * 32 + h)) * 32 + w) * 64 + c) = *(uint4*)&l1[w][c];
    }
    if (he) {
        int o = t * 4;
        int w2 = o >> 6, c = o & 63;
        *(uint2*)(asc + (((size_t)(n * 16 + (h >> 1))) * 16 + w2) * 64 + c) = *(uint2*)&l2[w2][c];
    }
}

// Implicit-GEMM conv via MFMA 16x16x32 bf16 — 4-buffer ring, 3-deep prefetch.
// Tile: 128 co x 128 positions; 4 waves (2co x 2pos), each 64x64 (acc 4x4).
// K-step 32. Per iter: wait vmcnt(8) (oldest 4 chunks = this step's buffer),
// s_barrier, issue stage(s+3), ds_read buf[s&3], 16 MFMA (setprio 1).
// Stage(s+3) overwrites buf[(s-1)&3], last read before barrier(s) -> WAR-safe.
// OOB gather lanes read a 16B zero buffer (per-lane global address).
// Fused shortcut tail: KS_SC extra K-steps gathering from actsc
// (NHWC [N][16][16][64], 1x1, no pad), weights appended in wq.
// MODE 0: epilogue bn2+actq4 -> a2out (NHWC bf16 [N][16][16][128])
// MODE 1: write dout (fp32 NCHW)
template <int CIN, int KS_MAIN, int KS_SC, int STRIDE, int HIN, int MODE>
__global__ __launch_bounds__(256) void conv_mfma(
        const __bf16* __restrict__ act, const __bf16* __restrict__ actsc,
        const __bf16* __restrict__ wq,
        const float* __restrict__ sc2, const float* __restrict__ sh2,
        const __bf16* __restrict__ zerob,
        __bf16* __restrict__ a2out, float* __restrict__ dout) {
    __shared__ __align__(16) __bf16 Alds[4][128][32];   // [buf][co][k]  32 KB
    __shared__ __align__(16) __bf16 Blds[4][128][32];   // [buf][pos][k] 32 KB
    const int t = threadIdx.x;
    const int wv = t >> 6, l = t & 63;
    const int wco = wv >> 1, wp = wv & 1;
    const int lrow = l & 15, half = l >> 4;
    const int pbase = blockIdx.x * 128;
    const int n = pbase >> 8;            // wave-uniform: block covers half an image
    const int rbase = pbase & 255;       // 0 or 128

    f32x4 acc[4][4] = {};

    // B staging geometry: thread t stages 16B chunks t and 256+t.
    const int sub = (t & 3) * 8;
    const int pl = t >> 2;               // 0..63; chunk 256+t adds 64 -> +4 h-rows
    const int w2 = pl & 15;
    const int h20 = (rbase >> 4) + (pl >> 4);
    const int hi0b = STRIDE * h20 - 1;   // + kh
    const int hi1b = hi0b + 4 * STRIDE;  // position +64 => h2+4
    const int wib  = STRIDE * w2 - 1;    // + kw

    constexpr int CPS = CIN / 32;        // ci-chunks per (kh,kw)
    constexpr int KS = KS_MAIN + KS_SC;

    auto stage = [&](int s, int pg) {
        // A (weights, fully linear)
        const __bf16* gA = wq + (size_t)s * 4096 + t * 8;
        __bf16* lA = &Alds[pg][0][0] + wv * 512;
        gload16(gA, lA);
        gload16(gA + 2048, lA + 2048);
        // B (activation gather)
        __bf16* lB = &Blds[pg][0][0] + wv * 512;
        if (KS_SC == 0 || s < KS_MAIN) {
            int khw = s / CPS;
            int ci0 = (s % CPS) * 32;
            int kh = khw / 3, kw = khw - kh * 3;
            int hi0 = hi0b + kh, hi1 = hi1b + kh, wi = wib + kw;
            bool okw = (unsigned)wi < (unsigned)HIN;
            const __bf16* g0 = (okw && (unsigned)hi0 < (unsigned)HIN)
                ? act + ((size_t)(n * HIN + hi0) * HIN + wi) * CIN + ci0 + sub : zerob;
            const __bf16* g1 = (okw && (unsigned)hi1 < (unsigned)HIN)
                ? act + ((size_t)(n * HIN + hi1) * HIN + wi) * CIN + ci0 + sub : zerob;
            gload16(g0, lB);
            gload16(g1, lB + 2048);
        } else {
            int ci0 = (s - KS_MAIN) * 32;
            const __bf16* g0 = actsc + ((size_t)(n * 16 + h20) * 16 + w2) * 64 + ci0 + sub;
            gload16(g0, lB);
            gload16(g0 + 4096, lB + 2048);   // +4 h-rows * 16 * 64
        }
    };

    // prologue: 3 K-steps in flight (12 chunks/thread)
    stage(0, 0);
    stage(1, 1);
    stage(2, 2);
    for (int s = 0; s < KS; ++s) {
        // wait for this step's 4 chunks (oldest); keep the rest in flight
        if (s < KS - 2)      asm volatile("s_waitcnt vmcnt(8)" ::: "memory");
        else if (s == KS - 2) asm volatile("s_waitcnt vmcnt(4)" ::: "memory");
        else                 asm volatile("s_waitcnt vmcnt(0)" ::: "memory");
        __builtin_amdgcn_s_barrier();
        __builtin_amdgcn_sched_barrier(0);
        if (s + 3 < KS) stage(s + 3, (s + 3) & 3);
        const int cur = s & 3;
        bf16x8 af[4], bfr[4];
#pragma unroll
        for (int i = 0; i < 4; ++i)
            af[i] = *(const bf16x8*)&Alds[cur][wco * 64 + i * 16 + lrow][half * 8];
#pragma unroll
        for (int j = 0; j < 4; ++j)
            bfr[j] = *(const bf16x8*)&Blds[cur][wp * 64 + j * 16 + lrow][half * 8];
        __builtin_amdgcn_s_setprio(1);
#pragma unroll
        for (int i = 0; i < 4; ++i)
#pragma unroll
            for (int j = 0; j < 4; ++j)
                acc[i][j] = __builtin_amdgcn_mfma_f32_16x16x32_bf16(af[i], bfr[j], acc[i][j], 0, 0, 0);
        __builtin_amdgcn_s_setprio(0);
    }

    // epilogue: C/D layout col=lane&15 (pos), row=(lane>>4)*4+reg (co)
#pragma unroll
    for (int i = 0; i < 4; ++i) {
        const int co0 = wco * 64 + i * 16 + half * 4;
        float s2[4], h2v[4];
        if constexpr (MODE == 0) {
#pragma unroll
            for (int r = 0; r < 4; ++r) { s2[r] = sc2[co0 + r]; h2v[r] = sh2[co0 + r]; }
        }
#pragma unroll
        for (int j = 0; j < 4; ++j) {
            const int rr = rbase + wp * 64 + j * 16 + lrow;
            if constexpr (MODE == 0) {
                __bf16 tmp[4];
#pragma unroll
                for (int r = 0; r < 4; ++r) {
                    float v = acc[i][j][r] * s2[r] + h2v[r];
                    tmp[r] = (__bf16)(rintf(fminf(fmaxf(v, 0.f), 1.f) * 15.f) * (1.f / 15.f));
                }
                *(uint2*)(a2out + ((size_t)n * 256 + rr) * 128 + co0) = *(uint2*)tmp;
            } else {
#pragma unroll
                for (int r = 0; r < 4; ++r)
                    dout[((size_t)n * 128 + co0 + r) * 256 + rr] = acc[i][j][r];
            }
        }
    }
}

extern "C" void kernel_launch(void* const* d_in, const int* in_sizes, int n_in,
                              void* d_out, int out_size, void* d_ws, size_t ws_size,
                              hipStream_t stream) {
    const float* x   = (const float*)d_in[0];
    const float* w1  = (const float*)d_in[1];
    const float* w2  = (const float*)d_in[2];
    const float* wsw = (const float*)d_in[3];
    const float* g1  = (const float*)d_in[4];
    const float* b1  = (const float*)d_in[5];
    const float* m1  = (const float*)d_in[6];
    const float* v1  = (const float*)d_in[7];
    const float* g2  = (const float*)d_in[8];
    const float* b2  = (const float*)d_in[9];
    const float* m2  = (const float*)d_in[10];
    const float* v2  = (const float*)d_in[11];
    const float* gs  = (const float*)d_in[12];
    const float* bs  = (const float*)d_in[13];
    const float* ms  = (const float*)d_in[14];
    const float* vs  = (const float*)d_in[15];
    float* out = (float*)d_out;
    char* ws = (char*)d_ws;

    // ws layout (bytes)
    __bf16* zerob = (__bf16*)(ws);                      // 64 B zeros
    __bf16* a1  = (__bf16*)(ws + 64);                   // 256*32*32*64 bf16 = 32 MiB
    __bf16* a2  = (__bf16*)(ws + 64 + 33554432);        // 256*16*16*128 bf16 = 16 MiB
    __bf16* asc = (__bf16*)(ws + 64 + 50331648);        // 256*16*16*64 bf16 = 8 MiB
    __bf16* w1q = (__bf16*)(ws + 64 + 58720256);        // 18*128*32 bf16
    __bf16* w2q = (__bf16*)(ws + 64 + 58867712);        // 38*128*32 bf16 (w2 + ws tail)
    float*  bnp = (float*)(ws + 64 + 59179008);         // 512 floats
    float* wmax = (float*)(ws + 64 + 59181056);         // 2 floats

    k_init<<<1, 64, 0, stream>>>(wmax, (uint4*)zerob);
    k_wmax<<<32, 256, 0, stream>>>(w1, w2, wmax);
    k_bnprep<<<1, 128, 0, stream>>>(g1, b1, m1, v1, g2, b2, m2, v2, gs, bs, ms, vs, bnp);
    k_wq<64, 9, true><<<288, 256, 0, stream>>>(w1, w1q, wmax, 73728);
    k_wq<128, 9, true><<<576, 256, 0, stream>>>(w2, w2q, wmax + 1, 147456);
    k_wq<64, 1, false><<<32, 256, 0, stream>>>(wsw, w2q + 36 * 4096, nullptr, 8192);
    k_a1<<<8192, 256, 0, stream>>>(x, bnp, a1, asc);
    // conv1: 3x3 stride 2 pad 1 on a1 (K=576); epilogue bn2+actq4 -> a2
    conv_mfma<64, 18, 0, 2, 32, 0><<<512, 256, 0, stream>>>(
        a1, nullptr, w1q, bnp + 256, bnp + 384, zerob, a2, nullptr);
    // conv2: 3x3 stride 1 pad 1 on a2 (K=1152) + fused 1x1 shortcut (K=64) -> out
    conv_mfma<128, 36, 2, 1, 16, 1><<<512, 256, 0, stream>>>(
        a2, asc, w2q, nullptr, nullptr, zerob, nullptr, out);
}